// Round 11
// baseline (115.599 us; speedup 1.0000x reference)
//
#include <hip/hip_runtime.h>
#include <hip/hip_bf16.h>

#define NL  128   // layers (n)
#define DK  256   // d_in (k)
#define DO_ 256   // d_out (o)
#define MB  1024  // batch (m)

typedef __attribute__((ext_vector_type(4))) float f32x4;
typedef __attribute__((ext_vector_type(8))) short bf16x8;
typedef __attribute__((ext_vector_type(8))) unsigned short u16x8;

static __device__ __forceinline__ unsigned short f2bf(float f) {
  __hip_bfloat16 h = __float2bfloat16(f);
  return __builtin_bit_cast(unsigned short, h);
}

// async global->LDS DMA, 16B per lane: dest = ldsbase + lane*16 (wave-uniform base)
static __device__ __forceinline__ void gload_lds16(const void* g, void* l) {
  __builtin_amdgcn_global_load_lds(
      (const __attribute__((address_space(1))) void*)g,
      (__attribute__((address_space(3))) void*)l, 16, 0, 0);
}

// ---------------------------------------------------------------------------
// Prep: W[n][k][o] fp32 -> Wt in MFMA B-fragment order, bf16 (verified R4-R10):
//   elem offset = ((n*16+ob)*8 + s)*512 + (lhi*16+lrow)*8 + (k&7)
// so a wave's B-load for (ob, s) is ONE contiguous 1KB dwordx4 per lane.
// ---------------------------------------------------------------------------
__global__ __launch_bounds__(256) void wt_prep(const float* __restrict__ W,
                                               unsigned short* __restrict__ Wt) {
  const int n     = blockIdx.y;
  const int ktile = (blockIdx.x >> 2) * 64;
  const int otile = (blockIdx.x & 3) * 64;
  __shared__ float tile[64][65];  // +1 pad: conflict-free column reads
  const float* Wn = W + (size_t)n * DK * DO_;
  const int t  = threadIdx.x;
  const int lr = t >> 4;
  const int lc = (t & 15) * 4;
#pragma unroll
  for (int p = 0; p < 4; ++p) {
    const int k = p * 16 + lr;
    const float4 v = *(const float4*)(Wn + (size_t)(ktile + k) * DO_ + otile + lc);
    tile[k][lc + 0] = v.x; tile[k][lc + 1] = v.y;
    tile[k][lc + 2] = v.z; tile[k][lc + 3] = v.w;
  }
  __syncthreads();
  const int ol = t >> 2;            // local o 0..63
  const int o  = otile + ol;
  const int kq = t & 3;
  unsigned short* Wt_n = Wt + (size_t)n * DO_ * DK;
#pragma unroll
  for (int h = 0; h < 2; ++h) {
    u16x8 w;
#pragma unroll
    for (int j = 0; j < 8; ++j) w[j] = f2bf(tile[kq * 16 + h * 8 + j][ol]);
    const int kc = (ktile >> 3) + kq * 2 + h;   // global 8-k chunk id (0..31)
    const int ob = o >> 4, lrw = o & 15, s = kc >> 2, lh = kc & 3;
    *(u16x8*)(Wt_n + ((size_t)(ob * 8 + s) * 64 + lh * 16 + lrw) * 8) = w;
  }
}

// ---------------------------------------------------------------------------
// Main: T3 2-phase pipeline with global_load_lds (zero-VGPR, zero-convert
// staging). Block = (n, 64 m-rows as 4 tiles x 16), 256 thr / 4 o-waves.
// Per tile: {vmcnt(0); s_barrier; STAGE(t+1) -> in flight under compute;
// compute(t)}. LDS holds fp32 x, XOR-swizzled via pre-swizzled global source
// (rule #21: linear DMA dest + inverse-swizzled source + swizzled read).
// Convert fp32->bf16 at LDS-read time. B: 2-deep pipeline of coalesced 1KB
// loads from prefrag L2-resident Wt. Swapped MFMA -> float4 stores.
// XCD swizzle: bid&7 -> n in [xcd*16,+16): 2MB Wt slice per XCD L2.
// ---------------------------------------------------------------------------
__global__ __launch_bounds__(256, 5) void nlinear_mfma(
    const float* __restrict__ X, const unsigned short* __restrict__ Wt,
    const float* __restrict__ bias, float* __restrict__ out) {
  const int wid  = blockIdx.x;
  const int n    = (wid & 7) * 16 + ((wid >> 3) & 15);
  const int mg   = wid >> 7;          // 0..15, 64 rows each
  const int t    = threadIdx.x;
  const int wave = t >> 6;            // 0..3 = o-slice of 64
  const int lane = t & 63;
  const int lrow = lane & 15;
  const int lhi  = lane >> 4;
  const int mbase = mg * 64;

  __shared__ float buf[2][16][256];   // 2 x 16KB fp32, swizzled 16B slots

  const float* xb = X + ((size_t)mbase * NL + n) * DK;
  const unsigned short* Wn = Wt + (size_t)n * DO_ * DK;

  // stage tile tt into buf[b]: wave stages rows 4*wave..4*wave+3.
  // slot q of row r holds chunk q ^ (r&7)  (source pre-swizzle, dest linear)
#define STAGE(tt, b)                                                        \
  {                                                                         \
    _Pragma("unroll")                                                       \
    for (int i = 0; i < 4; ++i) {                                           \
      const int r = wave * 4 + i;                                           \
      const float* g = xb + ((size_t)((tt) * 16 + r) * NL) * DK +           \
                       ((lane ^ (r & 7)) << 2);                             \
      gload_lds16((const void*)g, (void*)&buf[b][r][0]);                    \
    }                                                                       \
  }

  // B-load: coalesced 1KB per instr from prefragmented, L2-resident Wt
#define BLOAD(s, oj) \
  (*(const bf16x8*)(Wn + ((size_t)((wave * 4 + (oj)) * 8 + (s)) * 64 + lane) * 8))

  // A-read swizzle constant: chunk p=8s+2*lhi of row lrow sits at slot p^(lrow&7)
  const int cl = ((lhi << 1) ^ (lrow & 7));

  // prologue: stage tile 0
  STAGE(0, 0);

#pragma unroll
  for (int tt = 0; tt < 4; ++tt) {
    const int cb = tt & 1;
    // tile tt's DMA done (and prior stores drained); then block-wide visible
    asm volatile("s_waitcnt vmcnt(0)" ::: "memory");
    __builtin_amdgcn_s_barrier();
    __builtin_amdgcn_sched_barrier(0);
    // issue next tile's DMA NOW — it flies under this tile's entire compute
    if (tt < 3) STAGE(tt + 1, cb ^ 1);

    const char* ar = (const char*)&buf[cb][0][0] + lrow * 1024;

    f32x4 acc[4];
#pragma unroll
    for (int oj = 0; oj < 4; ++oj) acc[oj] = (f32x4){0.f, 0.f, 0.f, 0.f};

    // 2-deep B prefetch pipeline (static indices)
    bf16x8 bA[4], bB[4];
#pragma unroll
    for (int oj = 0; oj < 4; ++oj) bA[oj] = BLOAD(0, oj);
#pragma unroll
    for (int oj = 0; oj < 4; ++oj) bB[oj] = BLOAD(1, oj);

#pragma unroll
    for (int s = 0; s < 8; ++s) {
      // A fragment: two conflict-free b128 reads (slots cl, cl^1), cvt to bf16
      const f32x4 alo = *(const f32x4*)(ar + s * 128 + (cl << 4));
      const f32x4 ahi = *(const f32x4*)(ar + s * 128 + ((cl ^ 1) << 4));
      u16x8 w;
#pragma unroll
      for (int e = 0; e < 4; ++e) { w[e] = f2bf(alo[e]); w[4 + e] = f2bf(ahi[e]); }
      const bf16x8 af = __builtin_bit_cast(bf16x8, w);

      const bool odd = (s & 1) != 0;
#pragma unroll
      for (int oj = 0; oj < 4; ++oj) {  // SWAPPED: D[o][m], lane regs = 4 contig o
        const bf16x8 bf = odd ? bB[oj] : bA[oj];
        acc[oj] = __builtin_amdgcn_mfma_f32_16x16x32_bf16(bf, af, acc[oj], 0, 0, 0);
      }
      if (s < 6) {  // refill consumed slot with s+2
        if (odd) {
#pragma unroll
          for (int oj = 0; oj < 4; ++oj) bB[oj] = BLOAD(s + 2, oj);
        } else {
#pragma unroll
          for (int oj = 0; oj < 4; ++oj) bA[oj] = BLOAD(s + 2, oj);
        }
      }
    }

    // epilogue: m = mbase + tt*16 + lrow, o = wave*64 + oj*16 + lhi*4 + r
    const float* bb = bias + n * DO_ + wave * 64 + lhi * 4;
    const int m = mbase + tt * 16 + lrow;
    float* orow = out + ((size_t)m * NL + n) * DO_ + wave * 64 + lhi * 4;
#pragma unroll
    for (int oj = 0; oj < 4; ++oj) {
      const f32x4 bv = *(const f32x4*)(bb + oj * 16);
      *(f32x4*)(orow + oj * 16) = acc[oj] + bv;
    }
  }
#undef STAGE
#undef BLOAD
}

// ---------------------------------------------------------------------------
// Fallback (only if ws too small for Wt): plain fp32, correct but slow.
// ---------------------------------------------------------------------------
__global__ __launch_bounds__(256) void nlinear_naive(
    const float* __restrict__ X, const float* __restrict__ W,
    const float* __restrict__ B, float* __restrict__ out) {
  const int n = blockIdx.y;
  const int m = blockIdx.x;
  const int o = threadIdx.x;
  __shared__ float xs[DK];
  xs[o] = X[((size_t)m * NL + n) * DK + o];
  __syncthreads();
  const float* Wn = W + (size_t)n * DK * DO_;
  float s = B[n * DO_ + o];
  for (int k = 0; k < DK; ++k) s = fmaf(xs[k], Wn[(size_t)k * DO_ + o], s);
  out[((size_t)m * NL + n) * DO_ + o] = s;
}

extern "C" void kernel_launch(void* const* d_in, const int* in_sizes, int n_in,
                              void* d_out, int out_size, void* d_ws, size_t ws_size,
                              hipStream_t stream) {
  const float* x = (const float*)d_in[0];
  const float* w = (const float*)d_in[1];
  const float* b = (const float*)d_in[2];
  float* out     = (float*)d_out;
  const size_t wt_bytes = (size_t)NL * DK * DO_ * sizeof(unsigned short);
  if (ws_size >= wt_bytes) {
    unsigned short* wt = (unsigned short*)d_ws;
    wt_prep<<<dim3(16, NL), 256, 0, stream>>>(w, wt);
    nlinear_mfma<<<dim3(2048), 256, 0, stream>>>(x, wt, b, out);
  } else {
    nlinear_naive<<<dim3(MB, NL), 256, 0, stream>>>(x, w, b, out);
  }
}

// Round 12
// 77.838 us; speedup vs baseline: 1.4851x; 1.4851x over previous
//
#include <hip/hip_runtime.h>
#include <hip/hip_bf16.h>

#define NL  128   // layers (n)
#define DK  256   // d_in (k)
#define DO_ 256   // d_out (o)
#define MB  1024  // batch (m)

typedef __attribute__((ext_vector_type(4))) float f32x4;
typedef __attribute__((ext_vector_type(8))) short bf16x8;
typedef __attribute__((ext_vector_type(8))) unsigned short u16x8;
typedef __attribute__((ext_vector_type(4))) unsigned short u16x4;

static __device__ __forceinline__ unsigned short f2bf(float f) {
  __hip_bfloat16 h = __float2bfloat16(f);
  return __builtin_bit_cast(unsigned short, h);
}

// ---------------------------------------------------------------------------
// Prep: W[n][k][o] fp32 -> Wt in MFMA B-fragment order, bf16 (verified R4-R11):
//   unit (o, kc[8-k chunk]) -> ob=o>>4, lrow=o&15, s=kc>>2, lhi=kc&3
//   elem offset = ((n*16+ob)*8 + s)*512 + (lhi*16+lrow)*8 + (k&7)
// so a wave's B-load for (ob, s) is ONE contiguous 1KB dwordx4 per lane.
// ---------------------------------------------------------------------------
__global__ __launch_bounds__(256) void wt_prep(const float* __restrict__ W,
                                               unsigned short* __restrict__ Wt) {
  const int n     = blockIdx.y;
  const int ktile = (blockIdx.x >> 2) * 64;
  const int otile = (blockIdx.x & 3) * 64;
  __shared__ float tile[64][65];  // +1 pad: conflict-free column reads
  const float* Wn = W + (size_t)n * DK * DO_;
  const int t  = threadIdx.x;
  const int lr = t >> 4;
  const int lc = (t & 15) * 4;
#pragma unroll
  for (int p = 0; p < 4; ++p) {
    const int k = p * 16 + lr;
    const float4 v = *(const float4*)(Wn + (size_t)(ktile + k) * DO_ + otile + lc);
    tile[k][lc + 0] = v.x; tile[k][lc + 1] = v.y;
    tile[k][lc + 2] = v.z; tile[k][lc + 3] = v.w;
  }
  __syncthreads();
  const int ol = t >> 2;            // local o 0..63
  const int o  = otile + ol;
  const int kq = t & 3;
  unsigned short* Wt_n = Wt + (size_t)n * DO_ * DK;
#pragma unroll
  for (int h = 0; h < 2; ++h) {
    u16x8 w;
#pragma unroll
    for (int j = 0; j < 8; ++j) w[j] = f2bf(tile[kq * 16 + h * 8 + j][ol]);
    const int kc = (ktile >> 3) + kq * 2 + h;   // global 8-k chunk id (0..31)
    const int ob = o >> 4, lrw = o & 15, s = kc >> 2, lh = kc & 3;
    *(u16x8*)(Wt_n + ((size_t)(ob * 8 + s) * 64 + lh * 16 + lrw) * 8) = w;
  }
}

// ---------------------------------------------------------------------------
// Main: EXACT R8 structure (best: 80 us) with ONE change — non-temporal
// output stores. out bypasses L2/L3 so the read set (x 134MB + Wt 17MB)
// stays Infinity-Cache-resident across graph replays; HBM then carries
// mostly the write stream. Everything else identical to R8.
// ---------------------------------------------------------------------------
__global__ __launch_bounds__(512, 4) void nlinear_mfma(
    const float* __restrict__ X, const unsigned short* __restrict__ Wt,
    const float* __restrict__ bias, float* __restrict__ out) {
  const int wid  = blockIdx.x;
  const int n    = (wid & 7) * 16 + ((wid >> 3) & 15);
  const int mg   = wid >> 7;          // 0..15, 64 rows each
  const int t    = threadIdx.x;
  const int wave = t >> 6;            // 0..7 = o-slice of 32
  const int lane = t & 63;
  const int lrow = lane & 15;
  const int lhi  = lane >> 4;
  const int mbase = mg * 64;

  __shared__ unsigned short Alds[64 * 256];  // 32 KB, 512B rows, swizzled slots

  // ---- stage: wave w loads rows w*8+j (j=0..7), lane takes k=lane*4 ----
  const float* xw = X + ((size_t)(mbase + wave * 8) * NL + n) * DK + lane * 4;
  f32x4 xv[8];
#pragma unroll
  for (int j = 0; j < 8; ++j)
    xv[j] = *(const f32x4*)(xw + (size_t)j * NL * DK);

  // bias: issue early, independent of everything
  const float* bb = bias + n * DO_ + wave * 32 + lhi * 4;
  f32x4 bv[2];
#pragma unroll
  for (int oj = 0; oj < 2; ++oj) bv[oj] = *(const f32x4*)(bb + oj * 16);

  char* ab = (char*)Alds;
#pragma unroll
  for (int j = 0; j < 8; ++j) {
    u16x4 h;
#pragma unroll
    for (int e = 0; e < 4; ++e) h[e] = f2bf(xv[j][e]);
    // row = wave*8+j; chunk c = lane>>1; slot = c ^ (row&7) = c ^ j  (verified)
    *(u16x4*)(ab + (wave * 8 + j) * 512 + (((lane >> 1) ^ j) << 4) + (lane & 1) * 8) = h;
  }
  __syncthreads();  // the only barrier

  const unsigned short* Wn = Wt + (size_t)n * DO_ * DK;

  f32x4 acc[4][2];
#pragma unroll
  for (int mt = 0; mt < 4; ++mt)
#pragma unroll
    for (int oj = 0; oj < 2; ++oj) acc[mt][oj] = (f32x4){0.f, 0.f, 0.f, 0.f};

  // B-load helper: coalesced 1KB per instr from prefragmented, L2-resident Wt
#define BLOAD(s, oj) \
  (*(const bf16x8*)(Wn + ((size_t)(((wave * 2 + (oj)) * 8) + (s)) * 64 + lane) * 8))

  // 2-deep explicit B prefetch pipeline (all indices compile-time: no scratch)
  bf16x8 bA0 = BLOAD(0, 0), bA1 = BLOAD(0, 1);
  bf16x8 bB0 = BLOAD(1, 0), bB1 = BLOAD(1, 1);

#pragma unroll
  for (int s = 0; s < 8; ++s) {
    const bf16x8 bc0 = (s & 1) ? bB0 : bA0;
    const bf16x8 bc1 = (s & 1) ? bB1 : bA1;
    if (s < 6) {  // refill the slot just consumed with s+2
      if (s & 1) { bB0 = BLOAD(s + 2, 0); bB1 = BLOAD(s + 2, 1); }
      else       { bA0 = BLOAD(s + 2, 0); bA1 = BLOAD(s + 2, 1); }
    }
    bf16x8 af[4];
#pragma unroll
    for (int mt = 0; mt < 4; ++mt) {
      const int row = mt * 16 + lrow;
      af[mt] = *(const bf16x8*)(ab + row * 512 + (((s * 4 + lhi) ^ (row & 7)) << 4));
    }
#pragma unroll
    for (int mt = 0; mt < 4; ++mt) {  // SWAPPED: D[o][m], lane regs = 4 contig o
      acc[mt][0] = __builtin_amdgcn_mfma_f32_16x16x32_bf16(bc0, af[mt], acc[mt][0], 0, 0, 0);
      acc[mt][1] = __builtin_amdgcn_mfma_f32_16x16x32_bf16(bc1, af[mt], acc[mt][1], 0, 0, 0);
    }
  }
#undef BLOAD

  // epilogue: m = mbase + mt*16 + lrow, o = wave*32 + oj*16 + lhi*4 + r
  // NON-TEMPORAL stores: bypass L2/L3 so reads stay cache-resident.
#pragma unroll
  for (int mt = 0; mt < 4; ++mt) {
    const int m = mbase + mt * 16 + lrow;
    float* orow = out + ((size_t)m * NL + n) * DO_ + wave * 32 + lhi * 4;
#pragma unroll
    for (int oj = 0; oj < 2; ++oj) {
      const f32x4 v = acc[mt][oj] + bv[oj];
      __builtin_nontemporal_store(v, (f32x4*)(orow + oj * 16));
    }
  }
}

// ---------------------------------------------------------------------------
// Fallback (only if ws too small for Wt): plain fp32, correct but slow.
// ---------------------------------------------------------------------------
__global__ __launch_bounds__(256) void nlinear_naive(
    const float* __restrict__ X, const float* __restrict__ W,
    const float* __restrict__ B, float* __restrict__ out) {
  const int n = blockIdx.y;
  const int m = blockIdx.x;
  const int o = threadIdx.x;
  __shared__ float xs[DK];
  xs[o] = X[((size_t)m * NL + n) * DK + o];
  __syncthreads();
  const float* Wn = W + (size_t)n * DK * DO_;
  float s = B[n * DO_ + o];
  for (int k = 0; k < DK; ++k) s = fmaf(xs[k], Wn[(size_t)k * DO_ + o], s);
  out[((size_t)m * NL + n) * DO_ + o] = s;
}

extern "C" void kernel_launch(void* const* d_in, const int* in_sizes, int n_in,
                              void* d_out, int out_size, void* d_ws, size_t ws_size,
                              hipStream_t stream) {
  const float* x = (const float*)d_in[0];
  const float* w = (const float*)d_in[1];
  const float* b = (const float*)d_in[2];
  float* out     = (float*)d_out;
  const size_t wt_bytes = (size_t)NL * DK * DO_ * sizeof(unsigned short);
  if (ws_size >= wt_bytes) {
    unsigned short* wt = (unsigned short*)d_ws;
    wt_prep<<<dim3(16, NL), 256, 0, stream>>>(w, wt);
    nlinear_mfma<<<dim3(2048), 512, 0, stream>>>(x, wt, b, out);
  } else {
    nlinear_naive<<<dim3(MB, NL), 256, 0, stream>>>(x, w, b, out);
  }
}